// Round 6
// baseline (58.994 us; speedup 1.0000x reference)
//
#include <hip/hip_runtime.h>

// Projector: out[b,k,d] = sum_l softmax_k( cos(p_k, x[b,l]) ) * x[b,l,d]
// B=4096, L=200, D=64, K=8, fp32.
// v6: no x LDS tile (ph2 re-reads x from global/L2); norms folded into score
// (raw-proto dots, rn_p = 1 VGPR); 3 barriers/block total; 32 KB LDS union
// (attn 9.6 KB, then reduce scratch); octet butterfly reduce (DPP + swz4).

#define LQ 200
#define DQ 64
#define KQ 8
#define SAS 12    // attn row stride in dwords (48 B: b128-aligned, <=2-way banks)

__device__ __forceinline__ float dppx1(float v) {   // lane ^ 1 (quad_perm [1,0,3,2])
    return __int_as_float(__builtin_amdgcn_update_dpp(0, __float_as_int(v), 0xB1, 0xF, 0xF, true));
}
__device__ __forceinline__ float dppx2(float v) {   // lane ^ 2 (quad_perm [2,3,0,1])
    return __int_as_float(__builtin_amdgcn_update_dpp(0, __float_as_int(v), 0x4E, 0xF, 0xF, true));
}
__device__ __forceinline__ float swz4(float v) {    // lane ^ 4 (ds_swizzle BitMode)
    return __int_as_float(__builtin_amdgcn_ds_swizzle(__float_as_int(v), 0x101F));
}
__device__ __forceinline__ float allred8(float v) { // all-reduce over octet (t&7)
    v += dppx1(v); v += dppx2(v); v += swz4(v); return v;
}
__device__ __forceinline__ float dot4f(float4 a, float4 b) {
    return a.x * b.x + a.y * b.y + a.z * b.z + a.w * b.w;
}
__device__ __forceinline__ void fma4(float4& acc, float a, float4 v) {
    acc.x += a * v.x; acc.y += a * v.y; acc.z += a * v.z; acc.w += a * v.w;
}
__device__ __forceinline__ void add4(float4& a, float4 v) {
    a.x += v.x; a.y += v.y; a.z += v.z; a.w += v.w;
}

// split butterfly over the 8 octet-lanes: s[8] = this lane's chunk-partials for
// all 8 k. Returns the full reduction for k == (t&7). (HW-verified v3/v5)
__device__ __forceinline__ float reduce_dots(const float* s, bool b1, bool b2, bool b3) {
    float T0 = (b1 ? s[1] : s[0]) + dppx1(b1 ? s[0] : s[1]);
    float T1 = (b1 ? s[3] : s[2]) + dppx1(b1 ? s[2] : s[3]);
    float T2 = (b1 ? s[5] : s[4]) + dppx1(b1 ? s[4] : s[5]);
    float T3 = (b1 ? s[7] : s[6]) + dppx1(b1 ? s[6] : s[7]);
    float K0 = (b2 ? T1 : T0) + dppx2(b2 ? T0 : T1);
    float K1 = (b2 ? T3 : T2) + dppx2(b2 ? T2 : T3);
    return (b3 ? K1 : K0) + swz4(b3 ? K0 : K1);
}

__global__ __launch_bounds__(256, 4) void projector_kernel(const float* __restrict__ x,
                                                           const float* __restrict__ proto,
                                                           float* __restrict__ out) {
    __shared__ __align__(16) float4 sc[2048];   // 32 KB: attn (first 9.6 KB), then scratch
    float* sAf = (float*)sc;

    const int b = blockIdx.x;
    const int t = threadIdx.x;

    // ph1 mapping: octet lane c = 8-float chunk = this lane's k; rp = row-pair
    const int c  = t & 7;
    const int rp = t >> 3;                 // 0..31
    const bool b1 = (c & 1) != 0;
    const bool b2 = (c & 2) != 0;
    const bool b3 = (c & 4) != 0;

    // ph2 mapping: d-quad qd, row-group rg
    const int qd = t & 15;
    const int rg = t >> 4;                 // 0..15

    const float4* p4  = (const float4*)proto;
    const float4* xb4 = (const float4*)(x + (size_t)b * (LQ * DQ));

    // ---- proto sumsq -> rn_p for this lane's k (folded into score later)
    float rnp;
    {
        float sp[KQ];
        #pragma unroll
        for (int k = 0; k < KQ; ++k) {
            float4 pa = p4[k * 16 + 2 * c], pb = p4[k * 16 + 2 * c + 1];
            sp[k] = dot4f(pa, pa) + dot4f(pb, pb);
        }
        rnp = __builtin_amdgcn_rsqf(fmaxf(reduce_dots(sp, b1, b2, b3), 1e-12f));
    }

    // ---- phase 1: all rows' scores + softmax -> sA (no x staging)
    #pragma unroll
    for (int rr = 0; rr < 4; ++rr) {
        const int r0 = rr * 64 + 2 * rp, r1 = r0 + 1;
        if (r0 < LQ) {
            float4 xA0 = xb4[r0 * 16 + 2 * c], xA1 = xb4[r0 * 16 + 2 * c + 1];
            float4 xB0 = xb4[r1 * 16 + 2 * c], xB1 = xb4[r1 * 16 + 2 * c + 1];

            float s0[KQ], s1[KQ];
            #pragma unroll
            for (int k = 0; k < KQ; ++k) {
                float4 pa = p4[k * 16 + 2 * c], pb = p4[k * 16 + 2 * c + 1];
                s0[k] = dot4f(xA0, pa) + dot4f(xA1, pb);
                s1[k] = dot4f(xB0, pa) + dot4f(xB1, pb);
            }
            float d0 = reduce_dots(s0, b1, b2, b3) * rnp;   // raw dot * rn_p, k = c
            float d1 = reduce_dots(s1, b1, b2, b3) * rnp;

            float sq0 = allred8(dot4f(xA0, xA0) + dot4f(xA1, xA1));
            float sq1 = allred8(dot4f(xB0, xB0) + dot4f(xB1, xB1));

            float e0 = __expf(d0 * __builtin_amdgcn_rsqf(fmaxf(sq0, 1e-12f)));
            float e1 = __expf(d1 * __builtin_amdgcn_rsqf(fmaxf(sq1, 1e-12f)));
            sAf[r0 * SAS + c] = e0 * __builtin_amdgcn_rcpf(allred8(e0));
            sAf[r1 * SAS + c] = e1 * __builtin_amdgcn_rcpf(allred8(e1));
        }
    }
    __syncthreads();   // barrier 1: attn ready

    // ---- phase 2: acc[k][d-quad] += attn[row][k] * x[row][d-quad]
    // x re-read from global (L2-hot, coalesced 1 KB/wave-instr); attn broadcast from LDS.
    float4 acc[KQ];
    #pragma unroll
    for (int k = 0; k < KQ; ++k) acc[k] = make_float4(0.f, 0.f, 0.f, 0.f);

    {
        int row = rg;                       // rows rg + 16*i
        float4 xv = xb4[row * 16 + qd];
        float4 a0 = *(const float4*)&sAf[row * SAS];
        float4 a1 = *(const float4*)&sAf[row * SAS + 4];
        #pragma unroll
        for (int i = 0; i < 13; ++i) {
            float4 nxv = xv, na0 = a0, na1 = a1;
            if (i + 1 < 13) {               // prefetch next row (clamped, in-bounds)
                const int nrow = min(row + 16, LQ - 1);
                nxv = xb4[nrow * 16 + qd];
                na0 = *(const float4*)&sAf[nrow * SAS];
                na1 = *(const float4*)&sAf[nrow * SAS + 4];
            }
            if (row < LQ) {                 // only i==12 can fail (rg >= 8)
                fma4(acc[0], a0.x, xv); fma4(acc[1], a0.y, xv);
                fma4(acc[2], a0.z, xv); fma4(acc[3], a0.w, xv);
                fma4(acc[4], a1.x, xv); fma4(acc[5], a1.y, xv);
                fma4(acc[6], a1.z, xv); fma4(acc[7], a1.w, xv);
            }
            xv = nxv; a0 = na0; a1 = na1; row += 16;
        }
    }
    __syncthreads();   // barrier 2: all sA reads done; scratch may overwrite

    // ---- final: rotation-swizzled scratch [k][rg][qd], reduce over rg
    #pragma unroll
    for (int k = 0; k < KQ; ++k)
        sc[(k * 16 + rg) * 16 + ((qd + rg) & 15)] = acc[k];
    __syncthreads();   // barrier 3: partials visible

    if (t < 128) {
        const int k = t >> 4, q = t & 15;
        float4 sum = make_float4(0.f, 0.f, 0.f, 0.f);
        #pragma unroll
        for (int g = 0; g < 16; ++g) add4(sum, sc[(k * 16 + g) * 16 + ((q + g) & 15)]);
        ((float4*)(out + (size_t)b * (KQ * DQ)))[k * 16 + q] = sum;
    }
}

extern "C" void kernel_launch(void* const* d_in, const int* in_sizes, int n_in,
                              void* d_out, int out_size, void* d_ws, size_t ws_size,
                              hipStream_t stream) {
    const float* x     = (const float*)d_in[0];   // [B, L, D] fp32
    const float* proto = (const float*)d_in[1];   // [K, D] fp32
    float* out = (float*)d_out;                   // [B, K, D] fp32

    const int Bn = in_sizes[0] / (LQ * DQ);       // 4096

    projector_kernel<<<Bn, 256, 0, stream>>>(x, proto, out);
}

// Round 7
// 43.935 us; speedup vs baseline: 1.3428x; 1.3428x over previous
//
#include <hip/hip_runtime.h>

// Projector: out[b,k,d] = sum_l softmax_k( cos(p_k, x[b,l]) ) * x[b,l,d]
// B=4096, L=200, D=64, K=8, fp32.
// v7: ONE WAVE PER BATCH. 4096 single-wave blocks, zero barriers, zero
// cross-wave traffic. Per 8-row step: coalesced loads -> register dots vs
// raw-proto hoard (norms folded) -> octet butterfly -> in-register softmax ->
// PV through 2 KB wave-private LDS bounce (lockstep-safe, no sync).
// acc = 8 VGPR/lane = final out[k][chunk]; no reduction, 2 b128 stores.

#define LQ 200
#define DQ 64
#define KQ 8
#define NSTEP 25   // 25 * 8 rows = 200, no tail

__device__ __forceinline__ float dppx1(float v) {   // lane ^ 1 (quad_perm [1,0,3,2])
    return __int_as_float(__builtin_amdgcn_update_dpp(0, __float_as_int(v), 0xB1, 0xF, 0xF, true));
}
__device__ __forceinline__ float dppx2(float v) {   // lane ^ 2 (quad_perm [2,3,0,1])
    return __int_as_float(__builtin_amdgcn_update_dpp(0, __float_as_int(v), 0x4E, 0xF, 0xF, true));
}
__device__ __forceinline__ float swz4(float v) {    // lane ^ 4 (ds_swizzle BitMode)
    return __int_as_float(__builtin_amdgcn_ds_swizzle(__float_as_int(v), 0x101F));
}
__device__ __forceinline__ float allred8(float v) { // all-reduce over octet (t&7)
    v += dppx1(v); v += dppx2(v); v += swz4(v); return v;
}
__device__ __forceinline__ float dot4f(float4 a, float4 b) {
    return a.x * b.x + a.y * b.y + a.z * b.z + a.w * b.w;
}
__device__ __forceinline__ void fma4(float4& acc, float a, float4 v) {
    acc.x += a * v.x; acc.y += a * v.y; acc.z += a * v.z; acc.w += a * v.w;
}

// split butterfly over the 8 octet-lanes: s[8] = this lane's chunk-partials for
// all 8 k. Returns the full reduction for k == (t&7). (HW-verified v3/v5/v6)
__device__ __forceinline__ float reduce_dots(const float* s, bool b1, bool b2, bool b3) {
    float T0 = (b1 ? s[1] : s[0]) + dppx1(b1 ? s[0] : s[1]);
    float T1 = (b1 ? s[3] : s[2]) + dppx1(b1 ? s[2] : s[3]);
    float T2 = (b1 ? s[5] : s[4]) + dppx1(b1 ? s[4] : s[5]);
    float T3 = (b1 ? s[7] : s[6]) + dppx1(b1 ? s[6] : s[7]);
    float K0 = (b2 ? T1 : T0) + dppx2(b2 ? T0 : T1);
    float K1 = (b2 ? T3 : T2) + dppx2(b2 ? T2 : T3);
    return (b3 ? K1 : K0) + swz4(b3 ? K0 : K1);
}

__global__ __launch_bounds__(64, 3) void projector_kernel(const float* __restrict__ x,
                                                          const float* __restrict__ proto,
                                                          float* __restrict__ out) {
    __shared__ __align__(16) float xL[8 * DQ];   // 2 KB: 8 rows x 64 floats
    __shared__ __align__(16) float aL[8 * KQ];   // 256 B: attn [row][k]

    const int b = blockIdx.x;
    const int t = threadIdx.x;                   // 0..63, one wave
    const int c  = t & 7;                        // chunk id; also this lane's k (ph1)
    const int r8 = t >> 3;                       // row slot (ph1) / k (PV)
    const bool b1 = (c & 1) != 0;
    const bool b2 = (c & 2) != 0;
    const bool b3 = (c & 4) != 0;

    const float4* p4  = (const float4*)proto;
    const float4* xb4 = (const float4*)(x + (size_t)b * (LQ * DQ));

    // ---- raw-proto hoard (64 VGPR, loaded once; L1-broadcast reads) + rnp(k=c)
    float4 pA[KQ], pB[KQ];
    #pragma unroll
    for (int k = 0; k < KQ; ++k) {
        pA[k] = p4[k * 16 + 2 * c];
        pB[k] = p4[k * 16 + 2 * c + 1];
    }
    float rnp;
    {
        float sp[KQ];
        #pragma unroll
        for (int k = 0; k < KQ; ++k) sp[k] = dot4f(pA[k], pA[k]) + dot4f(pB[k], pB[k]);
        rnp = __builtin_amdgcn_rsqf(fmaxf(reduce_dots(sp, b1, b2, b3), 1e-12f));
    }

    // acc: this lane's final out[k=r8][chunk c] (8 floats)
    float4 acc0 = make_float4(0.f, 0.f, 0.f, 0.f), acc1 = acc0;

    // prefetch step 0: row r8, chunk c
    float4 xA = xb4[r8 * 16 + 2 * c], xB = xb4[r8 * 16 + 2 * c + 1];

    #pragma unroll 1
    for (int it = 0; it < NSTEP; ++it) {
        // ---- T14: issue next step's loads (clamped on last iter; values unused)
        const int nr = (it + 1 < NSTEP ? (it + 1) * 8 : (NSTEP - 1) * 8) + r8;
        float4 nA = xb4[nr * 16 + 2 * c];
        float4 nB = xb4[nr * 16 + 2 * c + 1];

        // ---- dots from registers; butterfly; softmax (all in-register)
        float s[KQ];
        #pragma unroll
        for (int k = 0; k < KQ; ++k)
            s[k] = dot4f(xA, pA[k]) + dot4f(xB, pB[k]);
        float d  = reduce_dots(s, b1, b2, b3) * rnp;              // raw dot * rn_p, k=c
        float sq = allred8(dot4f(xA, xA) + dot4f(xB, xB));        // row sumsq
        float e  = __expf(d * __builtin_amdgcn_rsqf(fmaxf(sq, 1e-12f)));
        float a  = e * __builtin_amdgcn_rcpf(allred8(e));          // attn[row r8][k=c]

        // ---- bounce to wave-private LDS (lockstep: no sync needed)
        ((float4*)xL)[r8 * 16 + 2 * c]     = xA;
        ((float4*)xL)[r8 * 16 + 2 * c + 1] = xB;
        aL[t] = a;                                                 // aL[r8*8 + c]

        // ---- PV: lane (k=r8, chunk c): acc += attn[r][k] * x[r][chunk]
        #pragma unroll
        for (int r = 0; r < 8; ++r) {
            float  av  = aL[r * KQ + r8];                 // b32 broadcast
            float4 xv0 = ((const float4*)xL)[r * 16 + 2 * c];      // conflict-free
            float4 xv1 = ((const float4*)xL)[r * 16 + 2 * c + 1];
            fma4(acc0, av, xv0);
            fma4(acc1, av, xv1);
        }

        xA = nA; xB = nB;
    }

    // ---- store: lane (k=r8, chunk c) owns out[b][r8][8c..8c+8) — coalesced 2 KB
    float4* og = (float4*)(out + (size_t)b * (KQ * DQ));
    og[r8 * 16 + 2 * c]     = acc0;
    og[r8 * 16 + 2 * c + 1] = acc1;
}

extern "C" void kernel_launch(void* const* d_in, const int* in_sizes, int n_in,
                              void* d_out, int out_size, void* d_ws, size_t ws_size,
                              hipStream_t stream) {
    const float* x     = (const float*)d_in[0];   // [B, L, D] fp32
    const float* proto = (const float*)d_in[1];   // [K, D] fp32
    float* out = (float*)d_out;                   // [B, K, D] fp32

    const int Bn = in_sizes[0] / (LQ * DQ);       // 4096

    projector_kernel<<<Bn, 64, 0, stream>>>(x, proto, out);
}